// Round 2
// baseline (5299.686 us; speedup 1.0000x reference)
//
#include <hip/hip_runtime.h>
#include <hip/hip_bf16.h>
#include <cstdint>

#define NEG_SLOPE 0.2f

// ---------- helpers: order-preserving float<->uint encode for atomicMax ----------
__device__ __forceinline__ unsigned fenc(float f) {
    unsigned u = __float_as_uint(f);
    return (u & 0x80000000u) ? ~u : (u | 0x80000000u);
}
__device__ __forceinline__ float fdec(unsigned u) {
    return (u & 0x80000000u) ? __uint_as_float(u & 0x7fffffffu) : __uint_as_float(~u);
}

// ---------- fp32 tiled GEMM: C[N,M] = A[N,K] @ B[K,M] (+bias, relu optional) ----------
__global__ __launch_bounds__(256) void gemm_kernel(
    const float* __restrict__ A, const float* __restrict__ B,
    const float* __restrict__ bias, float* __restrict__ C,
    int N, int K, int M, int fuse_bias_relu)
{
    __shared__ float As[16][65];   // [k][row], padded
    __shared__ float Bs[16][64];   // [k][col]
    const int tid = threadIdx.x;
    const int tx = tid & 15, ty = tid >> 4;
    const int row0 = blockIdx.y * 64, col0 = blockIdx.x * 64;
    float acc[4][4] = {};
    const int nk = (K + 15) >> 4;
    const bool k4 = ((K & 3) == 0);
    for (int kt = 0; kt < nk; ++kt) {
        const int k0 = kt << 4;
        // A tile: r = tid>>2 (0..63), kq = (tid&3)*4
        {
            int r = tid >> 2, kq = (tid & 3) << 2;
            int gr = row0 + r;
            float v0 = 0, v1 = 0, v2 = 0, v3 = 0;
            if (gr < N) {
                const float* ap = A + (size_t)gr * K + k0 + kq;
                if (k4 && (k0 + kq + 3 < K)) {
                    float4 v = *reinterpret_cast<const float4*>(ap);
                    v0 = v.x; v1 = v.y; v2 = v.z; v3 = v.w;
                } else {
                    int rem = K - (k0 + kq);
                    if (rem > 0) v0 = ap[0];
                    if (rem > 1) v1 = ap[1];
                    if (rem > 2) v2 = ap[2];
                    if (rem > 3) v3 = ap[3];
                }
            }
            As[kq + 0][r] = v0; As[kq + 1][r] = v1;
            As[kq + 2][r] = v2; As[kq + 3][r] = v3;
        }
        // B tile: kr = tid>>4 (0..15), cq = (tid&15)*4
        {
            int kr = tid >> 4, cq = (tid & 15) << 2;
            float4 v = make_float4(0.f, 0.f, 0.f, 0.f);
            if (k0 + kr < K)
                v = *reinterpret_cast<const float4*>(&B[(size_t)(k0 + kr) * M + col0 + cq]);
            *reinterpret_cast<float4*>(&Bs[kr][cq]) = v;
        }
        __syncthreads();
        #pragma unroll
        for (int kk = 0; kk < 16; ++kk) {
            float a0 = As[kk][ty * 4 + 0], a1 = As[kk][ty * 4 + 1];
            float a2 = As[kk][ty * 4 + 2], a3 = As[kk][ty * 4 + 3];
            float b0 = Bs[kk][tx * 4 + 0], b1 = Bs[kk][tx * 4 + 1];
            float b2 = Bs[kk][tx * 4 + 2], b3 = Bs[kk][tx * 4 + 3];
            acc[0][0] += a0 * b0; acc[0][1] += a0 * b1; acc[0][2] += a0 * b2; acc[0][3] += a0 * b3;
            acc[1][0] += a1 * b0; acc[1][1] += a1 * b1; acc[1][2] += a1 * b2; acc[1][3] += a1 * b3;
            acc[2][0] += a2 * b0; acc[2][1] += a2 * b1; acc[2][2] += a2 * b2; acc[2][3] += a2 * b3;
            acc[3][0] += a3 * b0; acc[3][1] += a3 * b1; acc[3][2] += a3 * b2; acc[3][3] += a3 * b3;
        }
        __syncthreads();
    }
    #pragma unroll
    for (int i = 0; i < 4; ++i) {
        int gr = row0 + ty * 4 + i;
        if (gr >= N) continue;
        #pragma unroll
        for (int j = 0; j < 4; ++j) {
            int gc = col0 + tx * 4 + j;
            float v = acc[i][j];
            if (fuse_bias_relu) v = fmaxf(v + bias[gc], 0.0f);
            C[(size_t)gr * M + gc] = v;
        }
    }
}

// ---------- per-node attention coefficients: a_src[n,h], a_dst[n,h] ----------
template <int F>   // F = H*C, H=4; one wave per node
__global__ __launch_bounds__(256) void attn_coeff(
    const float* __restrict__ h, const float* __restrict__ att_src,
    const float* __restrict__ att_dst, float* __restrict__ a_src,
    float* __restrict__ a_dst, int N)
{
    constexpr int VPT = F / 64;
    constexpr int C = F / 4;
    int wave = (blockIdx.x * blockDim.x + threadIdx.x) >> 6;
    int lane = threadIdx.x & 63;
    if (wave >= N) return;
    int j0 = lane * VPT;
    int hd = j0 / C;
    float ps = 0.f, pd = 0.f;
    #pragma unroll
    for (int t = 0; t < VPT; ++t) {
        int j = j0 + t;
        float v = h[(size_t)wave * F + j];
        int c = j - hd * C;
        ps += v * att_src[hd * C + c];
        pd += v * att_dst[hd * C + c];
    }
    #pragma unroll
    for (int off = 8; off >= 1; off >>= 1) {
        ps += __shfl_xor(ps, off, 64);
        pd += __shfl_xor(pd, off, 64);
    }
    if ((lane & 15) == 0) {
        a_src[wave * 4 + hd] = ps;
        a_dst[wave * 4 + hd] = pd;
    }
}

// ---------- edge pass 1: e = leakyrelu(a_src[s]+a_dst[d]); segment max into mEnc ----------
__global__ __launch_bounds__(256) void edge_scores(
    const int* __restrict__ ei, const float* __restrict__ a_src,
    const float* __restrict__ a_dst, float* __restrict__ e,
    unsigned* __restrict__ mEnc, int E, int Etot)
{
    int i = blockIdx.x * blockDim.x + threadIdx.x;
    if (i >= Etot) return;
    int s, d;
    if (i < E) { s = ei[i]; d = ei[E + i]; } else { s = i - E; d = s; }
    #pragma unroll
    for (int hd = 0; hd < 4; ++hd) {
        float v = a_src[s * 4 + hd] + a_dst[d * 4 + hd];
        v = (v >= 0.f) ? v : NEG_SLOPE * v;
        e[(size_t)i * 4 + hd] = v;
        atomicMax(&mEnc[d * 4 + hd], fenc(v));
    }
}

// ---------- edge pass 2: ex = exp(e - m[dst]); denom[dst] += ex ----------
__global__ __launch_bounds__(256) void edge_exp(
    const int* __restrict__ ei, float* __restrict__ e,
    const unsigned* __restrict__ mEnc, float* __restrict__ denom, int E, int Etot)
{
    int i = blockIdx.x * blockDim.x + threadIdx.x;
    if (i >= Etot) return;
    int d = (i < E) ? ei[E + i] : (i - E);
    #pragma unroll
    for (int hd = 0; hd < 4; ++hd) {
        float m = fdec(mEnc[d * 4 + hd]);
        float ex = __expf(e[(size_t)i * 4 + hd] - m);
        e[(size_t)i * 4 + hd] = ex;
        atomicAdd(&denom[d * 4 + hd], ex);
    }
}

// ---------- message scatter: out[d,:] += h[s,:] * alpha ----------
template <int F>   // one wave per edge
__global__ __launch_bounds__(256) void scatter_msgs(
    const int* __restrict__ ei, const float* __restrict__ h,
    const float* __restrict__ e, const float* __restrict__ denom,
    float* __restrict__ out, int E, int Etot)
{
    constexpr int VPT = F / 64;
    constexpr int C = F / 4;
    int wave = (blockIdx.x * blockDim.x + threadIdx.x) >> 6;
    int lane = threadIdx.x & 63;
    if (wave >= Etot) return;
    int s, d;
    if (wave < E) { s = ei[wave]; d = ei[E + wave]; } else { s = wave - E; d = s; }
    int j0 = lane * VPT;
    int hd = j0 / C;
    float alpha = e[(size_t)wave * 4 + hd] / (denom[d * 4 + hd] + 1e-16f);
    #pragma unroll
    for (int t = 0; t < VPT; ++t) {
        int j = j0 + t;
        atomicAdd(&out[(size_t)d * F + j], h[(size_t)s * F + j] * alpha);
    }
}

// ---------- bias + relu, in place ----------
__global__ __launch_bounds__(256) void bias_relu(
    float* __restrict__ x, const float* __restrict__ bias, int total, int mask)
{
    int i = blockIdx.x * blockDim.x + threadIdx.x;
    if (i >= total) return;
    x[i] = fmaxf(x[i] + bias[i & mask], 0.0f);
}

// ---------- mean pool accumulate (F=128), one wave per node ----------
__global__ __launch_bounds__(256) void pool_kernel(
    const float* __restrict__ h2, const int* __restrict__ batch,
    float* __restrict__ pooled, float* __restrict__ counts, int N)
{
    int wave = (blockIdx.x * blockDim.x + threadIdx.x) >> 6;
    int lane = threadIdx.x & 63;
    if (wave >= N) return;
    int g = batch[wave];
    atomicAdd(&pooled[g * 128 + lane], h2[(size_t)wave * 128 + lane]);
    atomicAdd(&pooled[g * 128 + 64 + lane], h2[(size_t)wave * 128 + 64 + lane]);
    if (lane == 0) atomicAdd(&counts[g], 1.0f);
}

// ---------- classifier head: one wave per graph ----------
__global__ __launch_bounds__(256) void head_kernel(
    const float* __restrict__ pooled, const float* __restrict__ counts,
    const float* __restrict__ Wc, const float* __restrict__ bc,
    const float* __restrict__ Wf, const float* __restrict__ bf,
    float* __restrict__ out)
{
    int wave = (blockIdx.x * blockDim.x + threadIdx.x) >> 6;
    int lane = threadIdx.x & 63;
    if (wave >= 64) return;
    float inv = 1.0f / fmaxf(counts[wave], 1.0f);
    float p0 = pooled[wave * 128 + lane] * inv;
    float p1 = pooled[wave * 128 + 64 + lane] * inv;
    float a0 = p0 * Wc[lane * 2 + 0] + p1 * Wc[(lane + 64) * 2 + 0];
    float a1 = p0 * Wc[lane * 2 + 1] + p1 * Wc[(lane + 64) * 2 + 1];
    float ac = p0 * Wf[lane] + p1 * Wf[lane + 64];
    #pragma unroll
    for (int off = 32; off >= 1; off >>= 1) {
        a0 += __shfl_xor(a0, off, 64);
        a1 += __shfl_xor(a1, off, 64);
        ac += __shfl_xor(ac, off, 64);
    }
    if (lane == 0) {
        out[wave * 2 + 0] = a0 + bc[0];
        out[wave * 2 + 1] = a1 + bc[1];
        out[128 + wave] = 1.0f / (1.0f + __expf(-(ac + bf[0])));
    }
}

extern "C" void kernel_launch(void* const* d_in, const int* in_sizes, int n_in,
                              void* d_out, int out_size, void* d_ws, size_t ws_size,
                              hipStream_t stream)
{
    const float* x     = (const float*)d_in[0];
    const int*   ei    = (const int*)d_in[1];
    const int*   batch = (const int*)d_in[2];
    const float* W_in  = (const float*)d_in[3];
    const float* b_in  = (const float*)d_in[4];
    const float* W1    = (const float*)d_in[5];
    const float* as1   = (const float*)d_in[6];
    const float* ad1   = (const float*)d_in[7];
    const float* bias1 = (const float*)d_in[8];
    const float* W2    = (const float*)d_in[9];
    const float* as2   = (const float*)d_in[10];
    const float* ad2   = (const float*)d_in[11];
    const float* bias2 = (const float*)d_in[12];
    const float* Wc    = (const float*)d_in[13];
    const float* bc    = (const float*)d_in[14];
    const float* Wf    = (const float*)d_in[15];
    const float* bf    = (const float*)d_in[16];
    float* out = (float*)d_out;

    const int N    = in_sizes[2];          // 50000
    const int E    = in_sizes[1] / 2;      // 800000
    const int K0   = in_sizes[0] / N;      // 773
    const int Etot = E + N;
    const int HID = 256, OUTF = 128;

    char* ws = (char*)d_ws;
    size_t off = 0;
    auto alloc = [&](size_t bytes) -> void* {
        void* p = ws + off;
        off = (off + bytes + 255) & ~(size_t)255;
        return p;
    };
    float*    B0     = (float*)alloc((size_t)N * HID * 4);      // h0 -> out1 -> h1
    float*    B1     = (float*)alloc((size_t)N * HID * 4);      // hc1 -> hc2 | out2
    float*    ebuf   = (float*)alloc((size_t)Etot * 4 * 4);     // e / ex per edge,head
    float*    a_src  = (float*)alloc((size_t)N * 4 * 4);
    float*    a_dst  = (float*)alloc((size_t)N * 4 * 4);
    unsigned* mEnc   = (unsigned*)alloc((size_t)N * 4 * 4);
    float*    denom  = (float*)alloc((size_t)N * 4 * 4);
    float*    pooled = (float*)alloc(64 * 128 * 4);
    float*    counts = (float*)alloc(64 * 4);
    (void)ws_size; (void)n_in; (void)out_size;

    dim3 blk(256);
    dim3 gEdge((Etot + 255) / 256);
    dim3 gEdgeWave((Etot + 3) / 4);
    dim3 gNodeWave((N + 3) / 4);

    // ---- input projection: h0 = relu(x @ W_in + b_in) ----
    gemm_kernel<<<dim3(HID / 64, (N + 63) / 64), blk, 0, stream>>>(x, W_in, b_in, B0, N, K0, HID, 1);

    // ---- GAT conv 1 ----
    gemm_kernel<<<dim3(HID / 64, (N + 63) / 64), blk, 0, stream>>>(B0, W1, nullptr, B1, N, HID, HID, 0);
    attn_coeff<256><<<gNodeWave, blk, 0, stream>>>(B1, as1, ad1, a_src, a_dst, N);
    hipMemsetAsync(mEnc, 0, (size_t)N * 4 * 4 * 2, stream);   // mEnc + denom (contiguous)
    edge_scores<<<gEdge, blk, 0, stream>>>(ei, a_src, a_dst, ebuf, mEnc, E, Etot);
    edge_exp<<<gEdge, blk, 0, stream>>>(ei, ebuf, mEnc, denom, E, Etot);
    hipMemsetAsync(B0, 0, (size_t)N * HID * 4, stream);
    scatter_msgs<256><<<gEdgeWave, blk, 0, stream>>>(ei, B1, ebuf, denom, B0, E, Etot);
    bias_relu<<<dim3((N * HID + 255) / 256), blk, 0, stream>>>(B0, bias1, N * HID, 255);

    // ---- GAT conv 2 ----
    float* hc2  = B1;
    float* out2 = B1 + (size_t)N * OUTF;
    gemm_kernel<<<dim3(OUTF / 64, (N + 63) / 64), blk, 0, stream>>>(B0, W2, nullptr, hc2, N, HID, OUTF, 0);
    attn_coeff<128><<<gNodeWave, blk, 0, stream>>>(hc2, as2, ad2, a_src, a_dst, N);
    hipMemsetAsync(mEnc, 0, (size_t)N * 4 * 4 * 2, stream);
    edge_scores<<<gEdge, blk, 0, stream>>>(ei, a_src, a_dst, ebuf, mEnc, E, Etot);
    edge_exp<<<gEdge, blk, 0, stream>>>(ei, ebuf, mEnc, denom, E, Etot);
    hipMemsetAsync(out2, 0, (size_t)N * OUTF * 4, stream);
    scatter_msgs<128><<<gEdgeWave, blk, 0, stream>>>(ei, hc2, ebuf, denom, out2, E, Etot);
    bias_relu<<<dim3((N * OUTF + 255) / 256), blk, 0, stream>>>(out2, bias2, N * OUTF, 127);

    // ---- pool + head ----
    hipMemsetAsync(pooled, 0, 64 * 128 * 4 + 64 * 4, stream);
    pool_kernel<<<gNodeWave, blk, 0, stream>>>(out2, batch, pooled, counts, N);
    head_kernel<<<dim3(16), blk, 0, stream>>>(pooled, counts, Wc, bc, Wf, bf, out);
}

// Round 3
// 1457.700 us; speedup vs baseline: 3.6356x; 3.6356x over previous
//
#include <hip/hip_runtime.h>
#include <hip/hip_bf16.h>
#include <cstdint>

#define NEG_SLOPE 0.2f

// ---------- fp32 tiled GEMM: C[N,M] = A[N,K] @ B[K,M] (+bias, relu optional) ----------
__global__ __launch_bounds__(256) void gemm_kernel(
    const float* __restrict__ A, const float* __restrict__ B,
    const float* __restrict__ bias, float* __restrict__ C,
    int N, int K, int M, int fuse_bias_relu)
{
    __shared__ float As[16][65];   // [k][row], padded
    __shared__ float Bs[16][64];   // [k][col]
    const int tid = threadIdx.x;
    const int tx = tid & 15, ty = tid >> 4;
    const int row0 = blockIdx.y * 64, col0 = blockIdx.x * 64;
    float acc[4][4] = {};
    const int nk = (K + 15) >> 4;
    const bool k4 = ((K & 3) == 0);
    for (int kt = 0; kt < nk; ++kt) {
        const int k0 = kt << 4;
        {
            int r = tid >> 2, kq = (tid & 3) << 2;
            int gr = row0 + r;
            float v0 = 0, v1 = 0, v2 = 0, v3 = 0;
            if (gr < N) {
                const float* ap = A + (size_t)gr * K + k0 + kq;
                if (k4 && (k0 + kq + 3 < K)) {
                    float4 v = *reinterpret_cast<const float4*>(ap);
                    v0 = v.x; v1 = v.y; v2 = v.z; v3 = v.w;
                } else {
                    int rem = K - (k0 + kq);
                    if (rem > 0) v0 = ap[0];
                    if (rem > 1) v1 = ap[1];
                    if (rem > 2) v2 = ap[2];
                    if (rem > 3) v3 = ap[3];
                }
            }
            As[kq + 0][r] = v0; As[kq + 1][r] = v1;
            As[kq + 2][r] = v2; As[kq + 3][r] = v3;
        }
        {
            int kr = tid >> 4, cq = (tid & 15) << 2;
            float4 v = make_float4(0.f, 0.f, 0.f, 0.f);
            if (k0 + kr < K)
                v = *reinterpret_cast<const float4*>(&B[(size_t)(k0 + kr) * M + col0 + cq]);
            *reinterpret_cast<float4*>(&Bs[kr][cq]) = v;
        }
        __syncthreads();
        #pragma unroll
        for (int kk = 0; kk < 16; ++kk) {
            float a0 = As[kk][ty * 4 + 0], a1 = As[kk][ty * 4 + 1];
            float a2 = As[kk][ty * 4 + 2], a3 = As[kk][ty * 4 + 3];
            float b0 = Bs[kk][tx * 4 + 0], b1 = Bs[kk][tx * 4 + 1];
            float b2 = Bs[kk][tx * 4 + 2], b3 = Bs[kk][tx * 4 + 3];
            acc[0][0] += a0 * b0; acc[0][1] += a0 * b1; acc[0][2] += a0 * b2; acc[0][3] += a0 * b3;
            acc[1][0] += a1 * b0; acc[1][1] += a1 * b1; acc[1][2] += a1 * b2; acc[1][3] += a1 * b3;
            acc[2][0] += a2 * b0; acc[2][1] += a2 * b1; acc[2][2] += a2 * b2; acc[2][3] += a2 * b3;
            acc[3][0] += a3 * b0; acc[3][1] += a3 * b1; acc[3][2] += a3 * b2; acc[3][3] += a3 * b3;
        }
        __syncthreads();
    }
    #pragma unroll
    for (int i = 0; i < 4; ++i) {
        int gr = row0 + ty * 4 + i;
        if (gr >= N) continue;
        #pragma unroll
        for (int j = 0; j < 4; ++j) {
            int gc = col0 + tx * 4 + j;
            float v = acc[i][j];
            if (fuse_bias_relu) v = fmaxf(v + bias[gc], 0.0f);
            C[(size_t)gr * M + gc] = v;
        }
    }
}

// ---------- per-node attention coefficients: a_src[n,h], a_dst[n,h] ----------
template <int F>   // F = H*C, H=4; one wave per node
__global__ __launch_bounds__(256) void attn_coeff(
    const float* __restrict__ h, const float* __restrict__ att_src,
    const float* __restrict__ att_dst, float* __restrict__ a_src,
    float* __restrict__ a_dst, int N)
{
    constexpr int VPT = F / 64;
    constexpr int C = F / 4;
    int wave = (blockIdx.x * blockDim.x + threadIdx.x) >> 6;
    int lane = threadIdx.x & 63;
    if (wave >= N) return;
    int j0 = lane * VPT;
    int hd = j0 / C;
    float ps = 0.f, pd = 0.f;
    #pragma unroll
    for (int t = 0; t < VPT; ++t) {
        int j = j0 + t;
        float v = h[(size_t)wave * F + j];
        int c = j - hd * C;
        ps += v * att_src[hd * C + c];
        pd += v * att_dst[hd * C + c];
    }
    #pragma unroll
    for (int off = 8; off >= 1; off >>= 1) {
        ps += __shfl_xor(ps, off, 64);
        pd += __shfl_xor(pd, off, 64);
    }
    if ((lane & 15) == 0) {
        a_src[wave * 4 + hd] = ps;
        a_dst[wave * 4 + hd] = pd;
    }
}

// ---------- CSR build: histogram ----------
__global__ __launch_bounds__(256) void hist_kernel(
    const int* __restrict__ ei, int* __restrict__ counts, int E, int Etot)
{
    int i = blockIdx.x * blockDim.x + threadIdx.x;
    if (i >= Etot) return;
    int d = (i < E) ? ei[E + i] : (i - E);
    atomicAdd(&counts[d], 1);
}

// ---------- CSR build: 3-stage exclusive scan -> row_ptr ----------
__global__ __launch_bounds__(256) void scan1_kernel(
    const int* __restrict__ counts, int* __restrict__ row_ptr,
    int* __restrict__ partials, int N)
{
    __shared__ int sh[256];
    int tid = threadIdx.x;
    int i = blockIdx.x * 256 + tid;
    int v = (i < N) ? counts[i] : 0;
    sh[tid] = v;
    __syncthreads();
    #pragma unroll
    for (int off = 1; off < 256; off <<= 1) {
        int t = (tid >= off) ? sh[tid - off] : 0;
        __syncthreads();
        sh[tid] += t;
        __syncthreads();
    }
    if (i < N) row_ptr[i + 1] = sh[tid];          // within-block inclusive
    if (tid == 255) partials[blockIdx.x] = sh[255];
}

__global__ __launch_bounds__(256) void scan2_kernel(int* __restrict__ partials, int nb)
{
    __shared__ int sh[256];
    int tid = threadIdx.x;
    int v = (tid < nb) ? partials[tid] : 0;
    sh[tid] = v;
    __syncthreads();
    #pragma unroll
    for (int off = 1; off < 256; off <<= 1) {
        int t = (tid >= off) ? sh[tid - off] : 0;
        __syncthreads();
        sh[tid] += t;
        __syncthreads();
    }
    if (tid < nb) partials[tid] = sh[tid] - v;    // exclusive offset per block
}

__global__ __launch_bounds__(256) void scan3_kernel(
    int* __restrict__ row_ptr, const int* __restrict__ partials, int N)
{
    int i = blockIdx.x * 256 + threadIdx.x;
    if (i == 0) row_ptr[0] = 0;
    if (i < N) row_ptr[i + 1] += partials[i >> 8];
}

// ---------- CSR build: fill column (src) list ----------
__global__ __launch_bounds__(256) void fill_kernel(
    const int* __restrict__ ei, int* __restrict__ cursor,
    int* __restrict__ col, int E, int Etot)
{
    int i = blockIdx.x * blockDim.x + threadIdx.x;
    if (i >= Etot) return;
    int s, d;
    if (i < E) { s = ei[i]; d = ei[E + i]; } else { s = i - E; d = s; }
    int slot = atomicAdd(&cursor[d], 1);
    col[slot] = s;
}

// ---------- fused per-dst GAT aggregation: softmax + gather + bias + relu ----------
template <int F>   // one wave per destination node; C = F/4 per head
__global__ __launch_bounds__(256) void gat_aggregate(
    const int* __restrict__ row_ptr, const int* __restrict__ col,
    const float* __restrict__ h, const float* __restrict__ a_src,
    const float* __restrict__ a_dst, const float* __restrict__ bias,
    float* __restrict__ out, int N)
{
    constexpr int VPT = F / 64;
    int wave = (blockIdx.x * blockDim.x + threadIdx.x) >> 6;
    int lane = threadIdx.x & 63;
    if (wave >= N) return;
    const int d = wave;
    const int start = row_ptr[d], end = row_ptr[d + 1];

    float4 adv = *reinterpret_cast<const float4*>(&a_dst[d * 4]);
    const float ad[4] = {adv.x, adv.y, adv.z, adv.w};

    // pass 1: per-head max over incoming edges
    float m[4] = {-1e30f, -1e30f, -1e30f, -1e30f};
    for (int j = start + lane; j < end; j += 64) {
        int s = col[j];
        float4 asv = *reinterpret_cast<const float4*>(&a_src[s * 4]);
        float ev[4] = {asv.x + ad[0], asv.y + ad[1], asv.z + ad[2], asv.w + ad[3]};
        #pragma unroll
        for (int hd = 0; hd < 4; ++hd) {
            float e = ev[hd];
            e = (e >= 0.f) ? e : NEG_SLOPE * e;
            m[hd] = fmaxf(m[hd], e);
        }
    }
    #pragma unroll
    for (int off = 32; off >= 1; off >>= 1) {
        #pragma unroll
        for (int hd = 0; hd < 4; ++hd)
            m[hd] = fmaxf(m[hd], __shfl_xor(m[hd], off, 64));
    }

    // pass 2: per-head denominator
    float den[4] = {0.f, 0.f, 0.f, 0.f};
    for (int j = start + lane; j < end; j += 64) {
        int s = col[j];
        float4 asv = *reinterpret_cast<const float4*>(&a_src[s * 4]);
        float ev[4] = {asv.x + ad[0], asv.y + ad[1], asv.z + ad[2], asv.w + ad[3]};
        #pragma unroll
        for (int hd = 0; hd < 4; ++hd) {
            float e = ev[hd];
            e = (e >= 0.f) ? e : NEG_SLOPE * e;
            den[hd] += __expf(e - m[hd]);
        }
    }
    #pragma unroll
    for (int off = 32; off >= 1; off >>= 1) {
        #pragma unroll
        for (int hd = 0; hd < 4; ++hd)
            den[hd] += __shfl_xor(den[hd], off, 64);
    }

    // pass 3: alpha-weighted gather of h[src]
    const int hd_l = lane >> 4;                  // head owning this lane's columns
    const float mm = m[hd_l];
    const float iv = 1.0f / (den[hd_l] + 1e-16f);
    const float adh = ad[hd_l];
    float acc[VPT] = {};
    for (int j = start; j < end; ++j) {
        int s = col[j];
        float e = a_src[s * 4 + hd_l] + adh;
        e = (e >= 0.f) ? e : NEG_SLOPE * e;
        float alpha = __expf(e - mm) * iv;
        if constexpr (VPT == 4) {
            float4 hv = *reinterpret_cast<const float4*>(&h[(size_t)s * F + lane * 4]);
            acc[0] += hv.x * alpha; acc[1] += hv.y * alpha;
            acc[2] += hv.z * alpha; acc[3] += hv.w * alpha;
        } else {
            float2 hv = *reinterpret_cast<const float2*>(&h[(size_t)s * F + lane * 2]);
            acc[0] += hv.x * alpha; acc[1] += hv.y * alpha;
        }
    }
    #pragma unroll
    for (int t = 0; t < VPT; ++t) {
        int j = lane * VPT + t;
        out[(size_t)d * F + j] = fmaxf(acc[t] + bias[j], 0.0f);
    }
}

// ---------- mean pool accumulate (F=128), one wave per node ----------
__global__ __launch_bounds__(256) void pool_kernel(
    const float* __restrict__ h2, const int* __restrict__ batch,
    float* __restrict__ pooled, float* __restrict__ counts, int N)
{
    int wave = (blockIdx.x * blockDim.x + threadIdx.x) >> 6;
    int lane = threadIdx.x & 63;
    if (wave >= N) return;
    int g = batch[wave];
    atomicAdd(&pooled[g * 128 + lane], h2[(size_t)wave * 128 + lane]);
    atomicAdd(&pooled[g * 128 + 64 + lane], h2[(size_t)wave * 128 + 64 + lane]);
    if (lane == 0) atomicAdd(&counts[g], 1.0f);
}

// ---------- classifier head: one wave per graph ----------
__global__ __launch_bounds__(256) void head_kernel(
    const float* __restrict__ pooled, const float* __restrict__ counts,
    const float* __restrict__ Wc, const float* __restrict__ bc,
    const float* __restrict__ Wf, const float* __restrict__ bf,
    float* __restrict__ out)
{
    int wave = (blockIdx.x * blockDim.x + threadIdx.x) >> 6;
    int lane = threadIdx.x & 63;
    if (wave >= 64) return;
    float inv = 1.0f / fmaxf(counts[wave], 1.0f);
    float p0 = pooled[wave * 128 + lane] * inv;
    float p1 = pooled[wave * 128 + 64 + lane] * inv;
    float a0 = p0 * Wc[lane * 2 + 0] + p1 * Wc[(lane + 64) * 2 + 0];
    float a1 = p0 * Wc[lane * 2 + 1] + p1 * Wc[(lane + 64) * 2 + 1];
    float ac = p0 * Wf[lane] + p1 * Wf[lane + 64];
    #pragma unroll
    for (int off = 32; off >= 1; off >>= 1) {
        a0 += __shfl_xor(a0, off, 64);
        a1 += __shfl_xor(a1, off, 64);
        ac += __shfl_xor(ac, off, 64);
    }
    if (lane == 0) {
        out[wave * 2 + 0] = a0 + bc[0];
        out[wave * 2 + 1] = a1 + bc[1];
        out[128 + wave] = 1.0f / (1.0f + __expf(-(ac + bf[0])));
    }
}

extern "C" void kernel_launch(void* const* d_in, const int* in_sizes, int n_in,
                              void* d_out, int out_size, void* d_ws, size_t ws_size,
                              hipStream_t stream)
{
    const float* x     = (const float*)d_in[0];
    const int*   ei    = (const int*)d_in[1];
    const int*   batch = (const int*)d_in[2];
    const float* W_in  = (const float*)d_in[3];
    const float* b_in  = (const float*)d_in[4];
    const float* W1    = (const float*)d_in[5];
    const float* as1   = (const float*)d_in[6];
    const float* ad1   = (const float*)d_in[7];
    const float* bias1 = (const float*)d_in[8];
    const float* W2    = (const float*)d_in[9];
    const float* as2   = (const float*)d_in[10];
    const float* ad2   = (const float*)d_in[11];
    const float* bias2 = (const float*)d_in[12];
    const float* Wc    = (const float*)d_in[13];
    const float* bc    = (const float*)d_in[14];
    const float* Wf    = (const float*)d_in[15];
    const float* bf    = (const float*)d_in[16];
    float* out = (float*)d_out;

    const int N    = in_sizes[2];          // 50000
    const int E    = in_sizes[1] / 2;      // 800000
    const int K0   = in_sizes[0] / N;      // 773
    const int Etot = E + N;
    const int HID = 256, OUTF = 128;
    const int nb  = (N + 255) / 256;       // scan blocks

    char* ws = (char*)d_ws;
    size_t off = 0;
    auto alloc = [&](size_t bytes) -> void* {
        void* p = ws + off;
        off = (off + bytes + 255) & ~(size_t)255;
        return p;
    };
    float* B0      = (float*)alloc((size_t)N * HID * 4);    // h0 -> h1
    float* B1      = (float*)alloc((size_t)N * HID * 4);    // hc1 | hc2 + out2
    float* a_src   = (float*)alloc((size_t)N * 4 * 4);
    float* a_dst   = (float*)alloc((size_t)N * 4 * 4);
    int*   counts  = (int*)alloc((size_t)(N + 1) * 4);
    int*   row_ptr = (int*)alloc((size_t)(N + 1) * 4);
    int*   cursor  = (int*)alloc((size_t)N * 4);
    int*   colv    = (int*)alloc((size_t)Etot * 4);
    int*   partials= (int*)alloc(256 * 4);
    float* pooled  = (float*)alloc(64 * 128 * 4);
    float* gcounts = (float*)alloc(64 * 4);
    (void)ws_size; (void)n_in; (void)out_size;

    dim3 blk(256);
    dim3 gEdge((Etot + 255) / 256);
    dim3 gNodeWave((N + 3) / 4);
    dim3 gNodeTh((N + 255) / 256);

    // ---- CSR build (reused by both GAT layers) ----
    hipMemsetAsync(counts, 0, (size_t)(N + 1) * 4, stream);
    hist_kernel<<<gEdge, blk, 0, stream>>>(ei, counts, E, Etot);
    scan1_kernel<<<dim3(nb), blk, 0, stream>>>(counts, row_ptr, partials, N);
    scan2_kernel<<<dim3(1), blk, 0, stream>>>(partials, nb);
    scan3_kernel<<<gNodeTh, blk, 0, stream>>>(row_ptr, partials, N);
    hipMemcpyAsync(cursor, row_ptr, (size_t)N * 4, hipMemcpyDeviceToDevice, stream);
    fill_kernel<<<gEdge, blk, 0, stream>>>(ei, cursor, colv, E, Etot);

    // ---- input projection: h0 = relu(x @ W_in + b_in) ----
    gemm_kernel<<<dim3(HID / 64, (N + 63) / 64), blk, 0, stream>>>(x, W_in, b_in, B0, N, K0, HID, 1);

    // ---- GAT conv 1 ----
    gemm_kernel<<<dim3(HID / 64, (N + 63) / 64), blk, 0, stream>>>(B0, W1, nullptr, B1, N, HID, HID, 0);
    attn_coeff<256><<<gNodeWave, blk, 0, stream>>>(B1, as1, ad1, a_src, a_dst, N);
    gat_aggregate<256><<<gNodeWave, blk, 0, stream>>>(row_ptr, colv, B1, a_src, a_dst, bias1, B0, N);

    // ---- GAT conv 2 ----
    float* hc2  = B1;
    float* out2 = B1 + (size_t)N * OUTF;
    gemm_kernel<<<dim3(OUTF / 64, (N + 63) / 64), blk, 0, stream>>>(B0, W2, nullptr, hc2, N, HID, OUTF, 0);
    attn_coeff<128><<<gNodeWave, blk, 0, stream>>>(hc2, as2, ad2, a_src, a_dst, N);
    gat_aggregate<128><<<gNodeWave, blk, 0, stream>>>(row_ptr, colv, hc2, a_src, a_dst, bias2, out2, N);

    // ---- pool + head ----
    hipMemsetAsync(pooled, 0, 64 * 128 * 4 + 64 * 4, stream);
    pool_kernel<<<gNodeWave, blk, 0, stream>>>(out2, batch, pooled, gcounts, N);
    head_kernel<<<dim3(16), blk, 0, stream>>>(pooled, gcounts, Wc, bc, Wf, bf, out);
}

// Round 4
// 1073.370 us; speedup vs baseline: 4.9374x; 1.3581x over previous
//
#include <hip/hip_runtime.h>
#include <hip/hip_bf16.h>
#include <cstdint>

#define NEG_SLOPE 0.2f

// ---------- fp32 tiled GEMM: C[N,M] = A[N,K] @ B[K,M] (+bias, relu optional) ----------
__global__ __launch_bounds__(256) void gemm_kernel(
    const float* __restrict__ A, const float* __restrict__ B,
    const float* __restrict__ bias, float* __restrict__ C,
    int N, int K, int M, int fuse_bias_relu)
{
    __shared__ float As[16][65];   // [k][row], padded
    __shared__ float Bs[16][64];   // [k][col]
    const int tid = threadIdx.x;
    const int tx = tid & 15, ty = tid >> 4;
    const int row0 = blockIdx.y * 64, col0 = blockIdx.x * 64;
    float acc[4][4] = {};
    const int nk = (K + 15) >> 4;
    const bool k4 = ((K & 3) == 0);
    for (int kt = 0; kt < nk; ++kt) {
        const int k0 = kt << 4;
        {
            int r = tid >> 2, kq = (tid & 3) << 2;
            int gr = row0 + r;
            float v0 = 0, v1 = 0, v2 = 0, v3 = 0;
            if (gr < N) {
                const float* ap = A + (size_t)gr * K + k0 + kq;
                if (k4 && (k0 + kq + 3 < K)) {
                    float4 v = *reinterpret_cast<const float4*>(ap);
                    v0 = v.x; v1 = v.y; v2 = v.z; v3 = v.w;
                } else {
                    int rem = K - (k0 + kq);
                    if (rem > 0) v0 = ap[0];
                    if (rem > 1) v1 = ap[1];
                    if (rem > 2) v2 = ap[2];
                    if (rem > 3) v3 = ap[3];
                }
            }
            As[kq + 0][r] = v0; As[kq + 1][r] = v1;
            As[kq + 2][r] = v2; As[kq + 3][r] = v3;
        }
        {
            int kr = tid >> 4, cq = (tid & 15) << 2;
            float4 v = make_float4(0.f, 0.f, 0.f, 0.f);
            if (k0 + kr < K)
                v = *reinterpret_cast<const float4*>(&B[(size_t)(k0 + kr) * M + col0 + cq]);
            *reinterpret_cast<float4*>(&Bs[kr][cq]) = v;
        }
        __syncthreads();
        #pragma unroll
        for (int kk = 0; kk < 16; ++kk) {
            float a0 = As[kk][ty * 4 + 0], a1 = As[kk][ty * 4 + 1];
            float a2 = As[kk][ty * 4 + 2], a3 = As[kk][ty * 4 + 3];
            float b0 = Bs[kk][tx * 4 + 0], b1 = Bs[kk][tx * 4 + 1];
            float b2 = Bs[kk][tx * 4 + 2], b3 = Bs[kk][tx * 4 + 3];
            acc[0][0] += a0 * b0; acc[0][1] += a0 * b1; acc[0][2] += a0 * b2; acc[0][3] += a0 * b3;
            acc[1][0] += a1 * b0; acc[1][1] += a1 * b1; acc[1][2] += a1 * b2; acc[1][3] += a1 * b3;
            acc[2][0] += a2 * b0; acc[2][1] += a2 * b1; acc[2][2] += a2 * b2; acc[2][3] += a2 * b3;
            acc[3][0] += a3 * b0; acc[3][1] += a3 * b1; acc[3][2] += a3 * b2; acc[3][3] += a3 * b3;
        }
        __syncthreads();
    }
    #pragma unroll
    for (int i = 0; i < 4; ++i) {
        int gr = row0 + ty * 4 + i;
        if (gr >= N) continue;
        #pragma unroll
        for (int j = 0; j < 4; ++j) {
            int gc = col0 + tx * 4 + j;
            float v = acc[i][j];
            if (fuse_bias_relu) v = fmaxf(v + bias[gc], 0.0f);
            C[(size_t)gr * M + gc] = v;
        }
    }
}

// ---------- per-node attention coefficients: a_src[n,h], a_dst[n,h] ----------
template <int F>   // F = H*C, H=4; one wave per node
__global__ __launch_bounds__(256) void attn_coeff(
    const float* __restrict__ h, const float* __restrict__ att_src,
    const float* __restrict__ att_dst, float* __restrict__ a_src,
    float* __restrict__ a_dst, int N)
{
    constexpr int VPT = F / 64;
    constexpr int C = F / 4;
    int wave = (blockIdx.x * blockDim.x + threadIdx.x) >> 6;
    int lane = threadIdx.x & 63;
    if (wave >= N) return;
    int j0 = lane * VPT;
    int hd = j0 / C;
    float ps = 0.f, pd = 0.f;
    #pragma unroll
    for (int t = 0; t < VPT; ++t) {
        int j = j0 + t;
        float v = h[(size_t)wave * F + j];
        int c = j - hd * C;
        ps += v * att_src[hd * C + c];
        pd += v * att_dst[hd * C + c];
    }
    #pragma unroll
    for (int off = 8; off >= 1; off >>= 1) {
        ps += __shfl_xor(ps, off, 64);
        pd += __shfl_xor(pd, off, 64);
    }
    if ((lane & 15) == 0) {
        a_src[wave * 4 + hd] = ps;
        a_dst[wave * 4 + hd] = pd;
    }
}

// ---------- CSR build: histogram ----------
__global__ __launch_bounds__(256) void hist_kernel(
    const int* __restrict__ ei, int* __restrict__ counts, int E, int Etot)
{
    int i = blockIdx.x * blockDim.x + threadIdx.x;
    if (i >= Etot) return;
    int d = (i < E) ? ei[E + i] : (i - E);
    atomicAdd(&counts[d], 1);
}

// ---------- CSR build: 3-stage exclusive scan -> row_ptr ----------
__global__ __launch_bounds__(256) void scan1_kernel(
    const int* __restrict__ counts, int* __restrict__ row_ptr,
    int* __restrict__ partials, int N)
{
    __shared__ int sh[256];
    int tid = threadIdx.x;
    int i = blockIdx.x * 256 + tid;
    int v = (i < N) ? counts[i] : 0;
    sh[tid] = v;
    __syncthreads();
    #pragma unroll
    for (int off = 1; off < 256; off <<= 1) {
        int t = (tid >= off) ? sh[tid - off] : 0;
        __syncthreads();
        sh[tid] += t;
        __syncthreads();
    }
    if (i < N) row_ptr[i + 1] = sh[tid];          // within-block inclusive
    if (tid == 255) partials[blockIdx.x] = sh[255];
}

__global__ __launch_bounds__(256) void scan2_kernel(int* __restrict__ partials, int nb)
{
    __shared__ int sh[256];
    int tid = threadIdx.x;
    int v = (tid < nb) ? partials[tid] : 0;
    sh[tid] = v;
    __syncthreads();
    #pragma unroll
    for (int off = 1; off < 256; off <<= 1) {
        int t = (tid >= off) ? sh[tid - off] : 0;
        __syncthreads();
        sh[tid] += t;
        __syncthreads();
    }
    if (tid < nb) partials[tid] = sh[tid] - v;    // exclusive offset per block
}

__global__ __launch_bounds__(256) void scan3_kernel(
    int* __restrict__ row_ptr, const int* __restrict__ partials, int N)
{
    int i = blockIdx.x * 256 + threadIdx.x;
    if (i == 0) row_ptr[0] = 0;
    if (i < N) row_ptr[i + 1] += partials[i >> 8];
}

// ---------- CSR build: fill column (src) list ----------
__global__ __launch_bounds__(256) void fill_kernel(
    const int* __restrict__ ei, int* __restrict__ cursor,
    int* __restrict__ col, int E, int Etot)
{
    int i = blockIdx.x * blockDim.x + threadIdx.x;
    if (i >= Etot) return;
    int s, d;
    if (i < E) { s = ei[i]; d = ei[E + i]; } else { s = i - E; d = s; }
    int slot = atomicAdd(&cursor[d], 1);
    col[slot] = s;
}

// ---------- fused per-dst GAT aggregation: softmax + gather + bias + relu ----------
template <int F>   // one wave per destination node; C = F/4 per head
__global__ __launch_bounds__(256) void gat_aggregate(
    const int* __restrict__ row_ptr, const int* __restrict__ col,
    const float* __restrict__ h, const float* __restrict__ a_src,
    const float* __restrict__ a_dst, const float* __restrict__ bias,
    float* __restrict__ out, int N)
{
    constexpr int VPT = F / 64;
    int wave = (blockIdx.x * blockDim.x + threadIdx.x) >> 6;
    int lane = threadIdx.x & 63;
    if (wave >= N) return;
    const int d = wave;
    const int start = row_ptr[d], end = row_ptr[d + 1];

    float4 adv = *reinterpret_cast<const float4*>(&a_dst[d * 4]);
    const float ad[4] = {adv.x, adv.y, adv.z, adv.w};

    // pass 1: per-head max over incoming edges
    float m[4] = {-1e30f, -1e30f, -1e30f, -1e30f};
    for (int j = start + lane; j < end; j += 64) {
        int s = col[j];
        float4 asv = *reinterpret_cast<const float4*>(&a_src[s * 4]);
        float ev[4] = {asv.x + ad[0], asv.y + ad[1], asv.z + ad[2], asv.w + ad[3]};
        #pragma unroll
        for (int hd = 0; hd < 4; ++hd) {
            float e = ev[hd];
            e = (e >= 0.f) ? e : NEG_SLOPE * e;
            m[hd] = fmaxf(m[hd], e);
        }
    }
    #pragma unroll
    for (int off = 32; off >= 1; off >>= 1) {
        #pragma unroll
        for (int hd = 0; hd < 4; ++hd)
            m[hd] = fmaxf(m[hd], __shfl_xor(m[hd], off, 64));
    }

    // pass 2: per-head denominator
    float den[4] = {0.f, 0.f, 0.f, 0.f};
    for (int j = start + lane; j < end; j += 64) {
        int s = col[j];
        float4 asv = *reinterpret_cast<const float4*>(&a_src[s * 4]);
        float ev[4] = {asv.x + ad[0], asv.y + ad[1], asv.z + ad[2], asv.w + ad[3]};
        #pragma unroll
        for (int hd = 0; hd < 4; ++hd) {
            float e = ev[hd];
            e = (e >= 0.f) ? e : NEG_SLOPE * e;
            den[hd] += __expf(e - m[hd]);
        }
    }
    #pragma unroll
    for (int off = 32; off >= 1; off >>= 1) {
        #pragma unroll
        for (int hd = 0; hd < 4; ++hd)
            den[hd] += __shfl_xor(den[hd], off, 64);
    }

    // pass 3: alpha-weighted gather of h[src]
    const int hd_l = lane >> 4;                  // head owning this lane's columns
    const float mm = m[hd_l];
    const float iv = 1.0f / (den[hd_l] + 1e-16f);
    const float adh = ad[hd_l];
    float acc[VPT] = {};
    for (int j = start; j < end; ++j) {
        int s = col[j];
        float e = a_src[s * 4 + hd_l] + adh;
        e = (e >= 0.f) ? e : NEG_SLOPE * e;
        float alpha = __expf(e - mm) * iv;
        if constexpr (VPT == 4) {
            float4 hv = *reinterpret_cast<const float4*>(&h[(size_t)s * F + lane * 4]);
            acc[0] += hv.x * alpha; acc[1] += hv.y * alpha;
            acc[2] += hv.z * alpha; acc[3] += hv.w * alpha;
        } else {
            float2 hv = *reinterpret_cast<const float2*>(&h[(size_t)s * F + lane * 2]);
            acc[0] += hv.x * alpha; acc[1] += hv.y * alpha;
        }
    }
    #pragma unroll
    for (int t = 0; t < VPT; ++t) {
        int j = lane * VPT + t;
        out[(size_t)d * F + j] = fmaxf(acc[t] + bias[j], 0.0f);
    }
}

// ---------- mean pool: batch is SORTED -> register accumulate, flush on graph change ----------
#define POOL_RPW 64   // rows per wave
__global__ __launch_bounds__(256) void pool_kernel(
    const float* __restrict__ h2, const int* __restrict__ batch,
    float* __restrict__ pooled, float* __restrict__ counts, int N)
{
    int wave = (blockIdx.x * blockDim.x + threadIdx.x) >> 6;
    int lane = threadIdx.x & 63;
    int r0 = wave * POOL_RPW;
    if (r0 >= N) return;
    int r1 = min(r0 + POOL_RPW, N);
    int cur_g = batch[r0];
    float a0 = 0.f, a1 = 0.f, cnt = 0.f;
    for (int r = r0; r < r1; ++r) {
        int g = batch[r];
        if (g != cur_g) {
            atomicAdd(&pooled[cur_g * 128 + lane * 2 + 0], a0);
            atomicAdd(&pooled[cur_g * 128 + lane * 2 + 1], a1);
            if (lane == 0) atomicAdd(&counts[cur_g], cnt);
            a0 = a1 = cnt = 0.f;
            cur_g = g;
        }
        float2 hv = *reinterpret_cast<const float2*>(&h2[(size_t)r * 128 + lane * 2]);
        a0 += hv.x; a1 += hv.y; cnt += 1.f;
    }
    atomicAdd(&pooled[cur_g * 128 + lane * 2 + 0], a0);
    atomicAdd(&pooled[cur_g * 128 + lane * 2 + 1], a1);
    if (lane == 0) atomicAdd(&counts[cur_g], cnt);
}

// ---------- classifier head: one wave per graph ----------
__global__ __launch_bounds__(256) void head_kernel(
    const float* __restrict__ pooled, const float* __restrict__ counts,
    const float* __restrict__ Wc, const float* __restrict__ bc,
    const float* __restrict__ Wf, const float* __restrict__ bf,
    float* __restrict__ out)
{
    int wave = (blockIdx.x * blockDim.x + threadIdx.x) >> 6;
    int lane = threadIdx.x & 63;
    if (wave >= 64) return;
    float inv = 1.0f / fmaxf(counts[wave], 1.0f);
    float p0 = pooled[wave * 128 + lane] * inv;
    float p1 = pooled[wave * 128 + 64 + lane] * inv;
    float a0 = p0 * Wc[lane * 2 + 0] + p1 * Wc[(lane + 64) * 2 + 0];
    float a1 = p0 * Wc[lane * 2 + 1] + p1 * Wc[(lane + 64) * 2 + 1];
    float ac = p0 * Wf[lane] + p1 * Wf[lane + 64];
    #pragma unroll
    for (int off = 32; off >= 1; off >>= 1) {
        a0 += __shfl_xor(a0, off, 64);
        a1 += __shfl_xor(a1, off, 64);
        ac += __shfl_xor(ac, off, 64);
    }
    if (lane == 0) {
        out[wave * 2 + 0] = a0 + bc[0];
        out[wave * 2 + 1] = a1 + bc[1];
        out[128 + wave] = 1.0f / (1.0f + __expf(-(ac + bf[0])));
    }
}

extern "C" void kernel_launch(void* const* d_in, const int* in_sizes, int n_in,
                              void* d_out, int out_size, void* d_ws, size_t ws_size,
                              hipStream_t stream)
{
    const float* x     = (const float*)d_in[0];
    const int*   ei    = (const int*)d_in[1];
    const int*   batch = (const int*)d_in[2];
    const float* W_in  = (const float*)d_in[3];
    const float* b_in  = (const float*)d_in[4];
    const float* W1    = (const float*)d_in[5];
    const float* as1   = (const float*)d_in[6];
    const float* ad1   = (const float*)d_in[7];
    const float* bias1 = (const float*)d_in[8];
    const float* W2    = (const float*)d_in[9];
    const float* as2   = (const float*)d_in[10];
    const float* ad2   = (const float*)d_in[11];
    const float* bias2 = (const float*)d_in[12];
    const float* Wc    = (const float*)d_in[13];
    const float* bc    = (const float*)d_in[14];
    const float* Wf    = (const float*)d_in[15];
    const float* bf    = (const float*)d_in[16];
    float* out = (float*)d_out;

    const int N    = in_sizes[2];          // 50000
    const int E    = in_sizes[1] / 2;      // 800000
    const int K0   = in_sizes[0] / N;      // 773
    const int Etot = E + N;
    const int HID = 256, OUTF = 128;
    const int nb  = (N + 255) / 256;       // scan blocks

    char* ws = (char*)d_ws;
    size_t off = 0;
    auto alloc = [&](size_t bytes) -> void* {
        void* p = ws + off;
        off = (off + bytes + 255) & ~(size_t)255;
        return p;
    };
    float* B0      = (float*)alloc((size_t)N * HID * 4);    // h0 -> h1
    float* B1      = (float*)alloc((size_t)N * HID * 4);    // hc1 | hc2 + out2
    float* a_src   = (float*)alloc((size_t)N * 4 * 4);
    float* a_dst   = (float*)alloc((size_t)N * 4 * 4);
    int*   counts  = (int*)alloc((size_t)(N + 1) * 4);
    int*   row_ptr = (int*)alloc((size_t)(N + 1) * 4);
    int*   cursor  = (int*)alloc((size_t)N * 4);
    int*   colv    = (int*)alloc((size_t)Etot * 4);
    int*   partials= (int*)alloc(256 * 4);
    float* pooled  = (float*)alloc(64 * 128 * 4);
    float* gcounts = (float*)alloc(64 * 4);
    (void)ws_size; (void)n_in; (void)out_size;

    dim3 blk(256);
    dim3 gEdge((Etot + 255) / 256);
    dim3 gNodeWave((N + 3) / 4);
    dim3 gNodeTh((N + 255) / 256);
    dim3 gPool(((N + POOL_RPW - 1) / POOL_RPW + 3) / 4);

    // ---- CSR build (reused by both GAT layers) ----
    hipMemsetAsync(counts, 0, (size_t)(N + 1) * 4, stream);
    hist_kernel<<<gEdge, blk, 0, stream>>>(ei, counts, E, Etot);
    scan1_kernel<<<dim3(nb), blk, 0, stream>>>(counts, row_ptr, partials, N);
    scan2_kernel<<<dim3(1), blk, 0, stream>>>(partials, nb);
    scan3_kernel<<<gNodeTh, blk, 0, stream>>>(row_ptr, partials, N);
    hipMemcpyAsync(cursor, row_ptr, (size_t)N * 4, hipMemcpyDeviceToDevice, stream);
    fill_kernel<<<gEdge, blk, 0, stream>>>(ei, cursor, colv, E, Etot);

    // ---- input projection: h0 = relu(x @ W_in + b_in) ----
    gemm_kernel<<<dim3(HID / 64, (N + 63) / 64), blk, 0, stream>>>(x, W_in, b_in, B0, N, K0, HID, 1);

    // ---- GAT conv 1 ----
    gemm_kernel<<<dim3(HID / 64, (N + 63) / 64), blk, 0, stream>>>(B0, W1, nullptr, B1, N, HID, HID, 0);
    attn_coeff<256><<<gNodeWave, blk, 0, stream>>>(B1, as1, ad1, a_src, a_dst, N);
    gat_aggregate<256><<<gNodeWave, blk, 0, stream>>>(row_ptr, colv, B1, a_src, a_dst, bias1, B0, N);

    // ---- GAT conv 2 ----
    float* hc2  = B1;
    float* out2 = B1 + (size_t)N * OUTF;
    gemm_kernel<<<dim3(OUTF / 64, (N + 63) / 64), blk, 0, stream>>>(B0, W2, nullptr, hc2, N, HID, OUTF, 0);
    attn_coeff<128><<<gNodeWave, blk, 0, stream>>>(hc2, as2, ad2, a_src, a_dst, N);
    gat_aggregate<128><<<gNodeWave, blk, 0, stream>>>(row_ptr, colv, hc2, a_src, a_dst, bias2, out2, N);

    // ---- pool + head ----
    hipMemsetAsync(pooled, 0, 64 * 128 * 4 + 64 * 4, stream);
    pool_kernel<<<gPool, blk, 0, stream>>>(out2, batch, pooled, gcounts, N);
    head_kernel<<<dim3(16), blk, 0, stream>>>(pooled, gcounts, Wc, bc, Wf, bf, out);
}

// Round 5
// 917.325 us; speedup vs baseline: 5.7773x; 1.1701x over previous
//
#include <hip/hip_runtime.h>
#include <hip/hip_bf16.h>
#include <cstdint>

#define NEG_SLOPE 0.2f

typedef __attribute__((ext_vector_type(8))) short bf16x8;
typedef __attribute__((ext_vector_type(4))) float f32x4;

// ---------- bf16 helpers (manual RNE, bit-level) ----------
__device__ __forceinline__ unsigned short f2bf(float f) {
    unsigned u = __float_as_uint(f);
    unsigned r = (u + 0x7FFFu + ((u >> 16) & 1u)) >> 16;
    return (unsigned short)r;
}
__device__ __forceinline__ float bf2f(unsigned short h) {
    return __uint_as_float(((unsigned)h) << 16);
}
__device__ __forceinline__ void splitbf(float v, unsigned short& hi, unsigned short& lo) {
    hi = f2bf(v);
    lo = f2bf(v - bf2f(hi));
}

// ---------- weight prep: W [K][M] fp32 -> Bt_hi/Bt_lo [M][Kp] bf16 (transposed, padded) ----------
__global__ __launch_bounds__(256) void convertB(
    const float* __restrict__ W, unsigned short* __restrict__ bth,
    unsigned short* __restrict__ btl, int K, int M, int Kp)
{
    int idx = blockIdx.x * 256 + threadIdx.x;
    if (idx >= M * Kp) return;
    int m = idx / Kp, k = idx % Kp;
    float v = (k < K) ? W[(size_t)k * M + m] : 0.0f;
    unsigned short h, l;
    splitbf(v, h, l);
    bth[idx] = h; btl[idx] = l;
}

// ---------- split-bf16 MFMA GEMM: C[N,M] = A[N,K] @ B[K,M] ----------
// A fp32, split to hi/lo bf16 during LDS staging. B pre-split+transposed planar.
// 128x128 tile, 4 waves (2x2), each wave 64x64 via 4x4 frags of 16x16x32.
#define BM 128
#define BN 128
#define BK 32
#define PADK 40
__global__ __launch_bounds__(256) void gemm_split_mfma(
    const float* __restrict__ A, const unsigned short* __restrict__ Bth,
    const unsigned short* __restrict__ Btl, const float* __restrict__ bias,
    float* __restrict__ C, int N, int K, int Kp, int M, int fuse_bias_relu)
{
    __shared__ unsigned short sAh[BM][PADK], sAl[BM][PADK];
    __shared__ unsigned short sBh[BN][PADK], sBl[BN][PADK];
    const int tid = threadIdx.x;
    const int lane = tid & 63;
    const int wid = tid >> 6;
    const int wm = wid >> 1, wn = wid & 1;
    const int row0 = blockIdx.y * BM, col0 = blockIdx.x * BN;
    const bool k4 = ((K & 3) == 0);

    f32x4 acc[4][4];
    #pragma unroll
    for (int i = 0; i < 4; ++i)
        #pragma unroll
        for (int j = 0; j < 4; ++j)
            acc[i][j] = (f32x4)0.0f;

    for (int k0 = 0; k0 < Kp; k0 += BK) {
        __syncthreads();
        // ---- stage A: 128 rows x 32 k, split fp32 -> hi/lo bf16 ----
        #pragma unroll
        for (int i = 0; i < 4; ++i) {
            int flat = i * 256 + tid;       // 0..1023
            int r = flat >> 3;              // 0..127
            int ch = flat & 7;              // 4 floats per chunk
            int gr = row0 + r;
            int gk = k0 + ch * 4;
            float v0 = 0.f, v1 = 0.f, v2 = 0.f, v3 = 0.f;
            if (gr < N) {
                const float* ap = A + (size_t)gr * K + gk;
                if (k4) {                    // K multiple of 4: aligned float4
                    float4 v = *reinterpret_cast<const float4*>(ap);
                    v0 = v.x; v1 = v.y; v2 = v.z; v3 = v.w;
                } else {
                    if (gk + 0 < K) v0 = ap[0];
                    if (gk + 1 < K) v1 = ap[1];
                    if (gk + 2 < K) v2 = ap[2];
                    if (gk + 3 < K) v3 = ap[3];
                }
            }
            unsigned short h0, h1, h2, h3, l0, l1, l2, l3;
            splitbf(v0, h0, l0); splitbf(v1, h1, l1);
            splitbf(v2, h2, l2); splitbf(v3, h3, l3);
            *reinterpret_cast<ushort4*>(&sAh[r][ch * 4]) = make_ushort4(h0, h1, h2, h3);
            *reinterpret_cast<ushort4*>(&sAl[r][ch * 4]) = make_ushort4(l0, l1, l2, l3);
        }
        // ---- stage B: 128 m-rows x 32 k from planar [M][Kp] bf16 ----
        #pragma unroll
        for (int i = 0; i < 2; ++i) {
            int flat = i * 256 + tid;       // 0..511
            int r = flat >> 2;              // 0..127
            int ch = flat & 3;              // 8 bf16 per chunk
            size_t goff = (size_t)(col0 + r) * Kp + k0 + ch * 8;
            uint4 vh = *reinterpret_cast<const uint4*>(Bth + goff);
            uint4 vl = *reinterpret_cast<const uint4*>(Btl + goff);
            *reinterpret_cast<uint4*>(&sBh[r][ch * 8]) = vh;
            *reinterpret_cast<uint4*>(&sBl[r][ch * 8]) = vl;
        }
        __syncthreads();

        // ---- MFMA: 3 pairings (hi.hi + lo.hi + hi.lo) ----
        const int kb = (lane >> 4) * 8;
        const int rA = wm * 64 + (lane & 15);
        const int rB = wn * 64 + (lane & 15);
        bf16x8 ah[4], al[4];
        #pragma unroll
        for (int m = 0; m < 4; ++m) {
            ah[m] = *reinterpret_cast<const bf16x8*>(&sAh[rA + m * 16][kb]);
            al[m] = *reinterpret_cast<const bf16x8*>(&sAl[rA + m * 16][kb]);
        }
        #pragma unroll
        for (int n = 0; n < 4; ++n) {
            bf16x8 bh = *reinterpret_cast<const bf16x8*>(&sBh[rB + n * 16][kb]);
            bf16x8 bl = *reinterpret_cast<const bf16x8*>(&sBl[rB + n * 16][kb]);
            #pragma unroll
            for (int m = 0; m < 4; ++m) {
                acc[m][n] = __builtin_amdgcn_mfma_f32_16x16x32_bf16(ah[m], bh, acc[m][n], 0, 0, 0);
                acc[m][n] = __builtin_amdgcn_mfma_f32_16x16x32_bf16(al[m], bh, acc[m][n], 0, 0, 0);
                acc[m][n] = __builtin_amdgcn_mfma_f32_16x16x32_bf16(ah[m], bl, acc[m][n], 0, 0, 0);
            }
        }
    }

    // ---- C write: D layout col=lane&15, row=(lane>>4)*4+reg ----
    #pragma unroll
    for (int m = 0; m < 4; ++m) {
        #pragma unroll
        for (int n = 0; n < 4; ++n) {
            int col = col0 + wn * 64 + n * 16 + (lane & 15);
            #pragma unroll
            for (int r = 0; r < 4; ++r) {
                int row = row0 + wm * 64 + m * 16 + (lane >> 4) * 4 + r;
                if (row < N) {
                    float v = acc[m][n][r];
                    if (fuse_bias_relu) v = fmaxf(v + bias[col], 0.0f);
                    C[(size_t)row * M + col] = v;
                }
            }
        }
    }
}

// ---------- per-node attention coefficients: a_src[n,h], a_dst[n,h] ----------
template <int F>   // F = H*C, H=4; one wave per node
__global__ __launch_bounds__(256) void attn_coeff(
    const float* __restrict__ h, const float* __restrict__ att_src,
    const float* __restrict__ att_dst, float* __restrict__ a_src,
    float* __restrict__ a_dst, int N)
{
    constexpr int VPT = F / 64;
    constexpr int C = F / 4;
    int wave = (blockIdx.x * blockDim.x + threadIdx.x) >> 6;
    int lane = threadIdx.x & 63;
    if (wave >= N) return;
    int j0 = lane * VPT;
    int hd = j0 / C;
    float ps = 0.f, pd = 0.f;
    #pragma unroll
    for (int t = 0; t < VPT; ++t) {
        int j = j0 + t;
        float v = h[(size_t)wave * F + j];
        int c = j - hd * C;
        ps += v * att_src[hd * C + c];
        pd += v * att_dst[hd * C + c];
    }
    #pragma unroll
    for (int off = 8; off >= 1; off >>= 1) {
        ps += __shfl_xor(ps, off, 64);
        pd += __shfl_xor(pd, off, 64);
    }
    if ((lane & 15) == 0) {
        a_src[wave * 4 + hd] = ps;
        a_dst[wave * 4 + hd] = pd;
    }
}

// ---------- CSR build: histogram ----------
__global__ __launch_bounds__(256) void hist_kernel(
    const int* __restrict__ ei, int* __restrict__ counts, int E, int Etot)
{
    int i = blockIdx.x * blockDim.x + threadIdx.x;
    if (i >= Etot) return;
    int d = (i < E) ? ei[E + i] : (i - E);
    atomicAdd(&counts[d], 1);
}

// ---------- CSR build: 3-stage exclusive scan -> row_ptr ----------
__global__ __launch_bounds__(256) void scan1_kernel(
    const int* __restrict__ counts, int* __restrict__ row_ptr,
    int* __restrict__ partials, int N)
{
    __shared__ int sh[256];
    int tid = threadIdx.x;
    int i = blockIdx.x * 256 + tid;
    int v = (i < N) ? counts[i] : 0;
    sh[tid] = v;
    __syncthreads();
    #pragma unroll
    for (int off = 1; off < 256; off <<= 1) {
        int t = (tid >= off) ? sh[tid - off] : 0;
        __syncthreads();
        sh[tid] += t;
        __syncthreads();
    }
    if (i < N) row_ptr[i + 1] = sh[tid];
    if (tid == 255) partials[blockIdx.x] = sh[255];
}

__global__ __launch_bounds__(256) void scan2_kernel(int* __restrict__ partials, int nb)
{
    __shared__ int sh[256];
    int tid = threadIdx.x;
    int v = (tid < nb) ? partials[tid] : 0;
    sh[tid] = v;
    __syncthreads();
    #pragma unroll
    for (int off = 1; off < 256; off <<= 1) {
        int t = (tid >= off) ? sh[tid - off] : 0;
        __syncthreads();
        sh[tid] += t;
        __syncthreads();
    }
    if (tid < nb) partials[tid] = sh[tid] - v;
}

__global__ __launch_bounds__(256) void scan3_kernel(
    int* __restrict__ row_ptr, const int* __restrict__ partials, int N)
{
    int i = blockIdx.x * 256 + threadIdx.x;
    if (i == 0) row_ptr[0] = 0;
    if (i < N) row_ptr[i + 1] += partials[i >> 8];
}

// ---------- CSR build: fill column (src) list ----------
__global__ __launch_bounds__(256) void fill_kernel(
    const int* __restrict__ ei, int* __restrict__ cursor,
    int* __restrict__ col, int E, int Etot)
{
    int i = blockIdx.x * blockDim.x + threadIdx.x;
    if (i >= Etot) return;
    int s, d;
    if (i < E) { s = ei[i]; d = ei[E + i]; } else { s = i - E; d = s; }
    int slot = atomicAdd(&cursor[d], 1);
    col[slot] = s;
}

// ---------- fused per-dst GAT aggregation: softmax + gather + bias + relu ----------
template <int F>   // one wave per destination node; C = F/4 per head
__global__ __launch_bounds__(256) void gat_aggregate(
    const int* __restrict__ row_ptr, const int* __restrict__ col,
    const float* __restrict__ h, const float* __restrict__ a_src,
    const float* __restrict__ a_dst, const float* __restrict__ bias,
    float* __restrict__ out, int N)
{
    constexpr int VPT = F / 64;
    int wave = (blockIdx.x * blockDim.x + threadIdx.x) >> 6;
    int lane = threadIdx.x & 63;
    if (wave >= N) return;
    const int d = wave;
    const int start = row_ptr[d], end = row_ptr[d + 1];

    float4 adv = *reinterpret_cast<const float4*>(&a_dst[d * 4]);
    const float ad[4] = {adv.x, adv.y, adv.z, adv.w};

    float m[4] = {-1e30f, -1e30f, -1e30f, -1e30f};
    for (int j = start + lane; j < end; j += 64) {
        int s = col[j];
        float4 asv = *reinterpret_cast<const float4*>(&a_src[s * 4]);
        float ev[4] = {asv.x + ad[0], asv.y + ad[1], asv.z + ad[2], asv.w + ad[3]};
        #pragma unroll
        for (int hd = 0; hd < 4; ++hd) {
            float e = ev[hd];
            e = (e >= 0.f) ? e : NEG_SLOPE * e;
            m[hd] = fmaxf(m[hd], e);
        }
    }
    #pragma unroll
    for (int off = 32; off >= 1; off >>= 1) {
        #pragma unroll
        for (int hd = 0; hd < 4; ++hd)
            m[hd] = fmaxf(m[hd], __shfl_xor(m[hd], off, 64));
    }

    float den[4] = {0.f, 0.f, 0.f, 0.f};
    for (int j = start + lane; j < end; j += 64) {
        int s = col[j];
        float4 asv = *reinterpret_cast<const float4*>(&a_src[s * 4]);
        float ev[4] = {asv.x + ad[0], asv.y + ad[1], asv.z + ad[2], asv.w + ad[3]};
        #pragma unroll
        for (int hd = 0; hd < 4; ++hd) {
            float e = ev[hd];
            e = (e >= 0.f) ? e : NEG_SLOPE * e;
            den[hd] += __expf(e - m[hd]);
        }
    }
    #pragma unroll
    for (int off = 32; off >= 1; off >>= 1) {
        #pragma unroll
        for (int hd = 0; hd < 4; ++hd)
            den[hd] += __shfl_xor(den[hd], off, 64);
    }

    const int hd_l = lane >> 4;
    const float mm = m[hd_l];
    const float iv = 1.0f / (den[hd_l] + 1e-16f);
    const float adh = ad[hd_l];
    float acc[VPT] = {};
    for (int j = start; j < end; ++j) {
        int s = col[j];
        float e = a_src[s * 4 + hd_l] + adh;
        e = (e >= 0.f) ? e : NEG_SLOPE * e;
        float alpha = __expf(e - mm) * iv;
        if constexpr (VPT == 4) {
            float4 hv = *reinterpret_cast<const float4*>(&h[(size_t)s * F + lane * 4]);
            acc[0] += hv.x * alpha; acc[1] += hv.y * alpha;
            acc[2] += hv.z * alpha; acc[3] += hv.w * alpha;
        } else {
            float2 hv = *reinterpret_cast<const float2*>(&h[(size_t)s * F + lane * 2]);
            acc[0] += hv.x * alpha; acc[1] += hv.y * alpha;
        }
    }
    #pragma unroll
    for (int t = 0; t < VPT; ++t) {
        int j = lane * VPT + t;
        out[(size_t)d * F + j] = fmaxf(acc[t] + bias[j], 0.0f);
    }
}

// ---------- mean pool: batch is SORTED -> register accumulate, flush on graph change ----------
#define POOL_RPW 64
__global__ __launch_bounds__(256) void pool_kernel(
    const float* __restrict__ h2, const int* __restrict__ batch,
    float* __restrict__ pooled, float* __restrict__ counts, int N)
{
    int wave = (blockIdx.x * blockDim.x + threadIdx.x) >> 6;
    int lane = threadIdx.x & 63;
    int r0 = wave * POOL_RPW;
    if (r0 >= N) return;
    int r1 = min(r0 + POOL_RPW, N);
    int cur_g = batch[r0];
    float a0 = 0.f, a1 = 0.f, cnt = 0.f;
    for (int r = r0; r < r1; ++r) {
        int g = batch[r];
        if (g != cur_g) {
            atomicAdd(&pooled[cur_g * 128 + lane * 2 + 0], a0);
            atomicAdd(&pooled[cur_g * 128 + lane * 2 + 1], a1);
            if (lane == 0) atomicAdd(&counts[cur_g], cnt);
            a0 = a1 = cnt = 0.f;
            cur_g = g;
        }
        float2 hv = *reinterpret_cast<const float2*>(&h2[(size_t)r * 128 + lane * 2]);
        a0 += hv.x; a1 += hv.y; cnt += 1.f;
    }
    atomicAdd(&pooled[cur_g * 128 + lane * 2 + 0], a0);
    atomicAdd(&pooled[cur_g * 128 + lane * 2 + 1], a1);
    if (lane == 0) atomicAdd(&counts[cur_g], cnt);
}

// ---------- classifier head: one wave per graph ----------
__global__ __launch_bounds__(256) void head_kernel(
    const float* __restrict__ pooled, const float* __restrict__ counts,
    const float* __restrict__ Wc, const float* __restrict__ bc,
    const float* __restrict__ Wf, const float* __restrict__ bf,
    float* __restrict__ out)
{
    int wave = (blockIdx.x * blockDim.x + threadIdx.x) >> 6;
    int lane = threadIdx.x & 63;
    if (wave >= 64) return;
    float inv = 1.0f / fmaxf(counts[wave], 1.0f);
    float p0 = pooled[wave * 128 + lane] * inv;
    float p1 = pooled[wave * 128 + 64 + lane] * inv;
    float a0 = p0 * Wc[lane * 2 + 0] + p1 * Wc[(lane + 64) * 2 + 0];
    float a1 = p0 * Wc[lane * 2 + 1] + p1 * Wc[(lane + 64) * 2 + 1];
    float ac = p0 * Wf[lane] + p1 * Wf[lane + 64];
    #pragma unroll
    for (int off = 32; off >= 1; off >>= 1) {
        a0 += __shfl_xor(a0, off, 64);
        a1 += __shfl_xor(a1, off, 64);
        ac += __shfl_xor(ac, off, 64);
    }
    if (lane == 0) {
        out[wave * 2 + 0] = a0 + bc[0];
        out[wave * 2 + 1] = a1 + bc[1];
        out[128 + wave] = 1.0f / (1.0f + __expf(-(ac + bf[0])));
    }
}

extern "C" void kernel_launch(void* const* d_in, const int* in_sizes, int n_in,
                              void* d_out, int out_size, void* d_ws, size_t ws_size,
                              hipStream_t stream)
{
    const float* x     = (const float*)d_in[0];
    const int*   ei    = (const int*)d_in[1];
    const int*   batch = (const int*)d_in[2];
    const float* W_in  = (const float*)d_in[3];
    const float* b_in  = (const float*)d_in[4];
    const float* W1    = (const float*)d_in[5];
    const float* as1   = (const float*)d_in[6];
    const float* ad1   = (const float*)d_in[7];
    const float* bias1 = (const float*)d_in[8];
    const float* W2    = (const float*)d_in[9];
    const float* as2   = (const float*)d_in[10];
    const float* ad2   = (const float*)d_in[11];
    const float* bias2 = (const float*)d_in[12];
    const float* Wc    = (const float*)d_in[13];
    const float* bc    = (const float*)d_in[14];
    const float* Wf    = (const float*)d_in[15];
    const float* bf    = (const float*)d_in[16];
    float* out = (float*)d_out;

    const int N    = in_sizes[2];          // 50000
    const int E    = in_sizes[1] / 2;      // 800000
    const int K0   = in_sizes[0] / N;      // 773
    const int Etot = E + N;
    const int HID = 256, OUTF = 128;
    const int Kp0 = ((K0 + 31) / 32) * 32; // 800
    const int nb  = (N + 255) / 256;

    char* ws = (char*)d_ws;
    size_t off = 0;
    auto alloc = [&](size_t bytes) -> void* {
        void* p = ws + off;
        off = (off + bytes + 255) & ~(size_t)255;
        return p;
    };
    float* B0      = (float*)alloc((size_t)N * HID * 4);    // h0 -> h1
    float* B1      = (float*)alloc((size_t)N * HID * 4);    // hc1 | hc2 + out2
    float* a_src   = (float*)alloc((size_t)N * 4 * 4);
    float* a_dst   = (float*)alloc((size_t)N * 4 * 4);
    int*   counts  = (int*)alloc((size_t)(N + 1) * 4);
    int*   row_ptr = (int*)alloc((size_t)(N + 1) * 4);
    int*   cursor  = (int*)alloc((size_t)N * 4);
    int*   colv    = (int*)alloc((size_t)Etot * 4);
    int*   partials= (int*)alloc(256 * 4);
    float* pooled  = (float*)alloc(64 * 128 * 4);
    float* gcounts = (float*)alloc(64 * 4);
    unsigned short* Bth0 = (unsigned short*)alloc((size_t)HID * Kp0 * 2);
    unsigned short* Btl0 = (unsigned short*)alloc((size_t)HID * Kp0 * 2);
    unsigned short* Bth1 = (unsigned short*)alloc((size_t)HID * HID * 2);
    unsigned short* Btl1 = (unsigned short*)alloc((size_t)HID * HID * 2);
    unsigned short* Bth2 = (unsigned short*)alloc((size_t)OUTF * HID * 2);
    unsigned short* Btl2 = (unsigned short*)alloc((size_t)OUTF * HID * 2);
    (void)ws_size; (void)n_in; (void)out_size;

    dim3 blk(256);
    dim3 gEdge((Etot + 255) / 256);
    dim3 gNodeWave((N + 3) / 4);
    dim3 gNodeTh((N + 255) / 256);
    dim3 gPool(((N + POOL_RPW - 1) / POOL_RPW + 3) / 4);
    dim3 gGemmRows((N + BM - 1) / BM);

    // ---- weight split/transpose (tiny) ----
    convertB<<<dim3((HID * Kp0 + 255) / 256), blk, 0, stream>>>(W_in, Bth0, Btl0, K0, HID, Kp0);
    convertB<<<dim3((HID * HID + 255) / 256), blk, 0, stream>>>(W1, Bth1, Btl1, HID, HID, HID);
    convertB<<<dim3((OUTF * HID + 255) / 256), blk, 0, stream>>>(W2, Bth2, Btl2, HID, OUTF, HID);

    // ---- CSR build (reused by both GAT layers) ----
    hipMemsetAsync(counts, 0, (size_t)(N + 1) * 4, stream);
    hist_kernel<<<gEdge, blk, 0, stream>>>(ei, counts, E, Etot);
    scan1_kernel<<<dim3(nb), blk, 0, stream>>>(counts, row_ptr, partials, N);
    scan2_kernel<<<dim3(1), blk, 0, stream>>>(partials, nb);
    scan3_kernel<<<gNodeTh, blk, 0, stream>>>(row_ptr, partials, N);
    hipMemcpyAsync(cursor, row_ptr, (size_t)N * 4, hipMemcpyDeviceToDevice, stream);
    fill_kernel<<<gEdge, blk, 0, stream>>>(ei, cursor, colv, E, Etot);

    // ---- input projection: h0 = relu(x @ W_in + b_in) ----
    gemm_split_mfma<<<dim3(HID / BN, gGemmRows.x), blk, 0, stream>>>(
        x, Bth0, Btl0, b_in, B0, N, K0, Kp0, HID, 1);

    // ---- GAT conv 1 ----
    gemm_split_mfma<<<dim3(HID / BN, gGemmRows.x), blk, 0, stream>>>(
        B0, Bth1, Btl1, nullptr, B1, N, HID, HID, HID, 0);
    attn_coeff<256><<<gNodeWave, blk, 0, stream>>>(B1, as1, ad1, a_src, a_dst, N);
    gat_aggregate<256><<<gNodeWave, blk, 0, stream>>>(row_ptr, colv, B1, a_src, a_dst, bias1, B0, N);

    // ---- GAT conv 2 ----
    float* hc2  = B1;
    float* out2 = B1 + (size_t)N * OUTF;
    gemm_split_mfma<<<dim3(OUTF / BN, gGemmRows.x), blk, 0, stream>>>(
        B0, Bth2, Btl2, nullptr, hc2, N, HID, HID, OUTF, 0);
    attn_coeff<128><<<gNodeWave, blk, 0, stream>>>(hc2, as2, ad2, a_src, a_dst, N);
    gat_aggregate<128><<<gNodeWave, blk, 0, stream>>>(row_ptr, colv, hc2, a_src, a_dst, bias2, out2, N);

    // ---- pool + head ----
    hipMemsetAsync(pooled, 0, 64 * 128 * 4 + 64 * 4, stream);
    pool_kernel<<<gPool, blk, 0, stream>>>(out2, batch, pooled, gcounts, N);
    head_kernel<<<dim3(16), blk, 0, stream>>>(pooled, gcounts, Wc, bc, Wf, bf, out);
}